// Round 7
// baseline (143.220 us; speedup 1.0000x reference)
//
#include <hip/hip_runtime.h>
#include <hip/hip_bf16.h>

// Problem constants: B=8, T=128, n=127 neighbors, Q=K=64, H=4, O=H*K=256
#define NB 127

typedef __attribute__((ext_vector_type(8))) short bf16x8;
typedef __attribute__((ext_vector_type(4))) float f32x4;

// ws layout: packed bf16 MFMA fragments (A/B-frag lane layout is identical), 4 x 32KB.
// short-offsets:
#define WKP_S  0
#define WVP_S  16384
#define WQP_S  32768
#define WVQP_S 49152
#define WS_NEEDED ((size_t)(4 * 16384 * 2))

__device__ __forceinline__ short bfs(float f) {
  __hip_bfloat16 h = __float2bfloat16(f);
  return __builtin_bit_cast(short, h);
}
__device__ __forceinline__ unsigned packbf2(float a, float b) {
  unsigned lo = (unsigned short)bfs(a);
  unsigned hi = (unsigned short)bfs(b);
  return lo | (hi << 16);
}
// gather 8 consecutive floats -> bf16x8 fragment
__device__ __forceinline__ bf16x8 gath(const float* __restrict__ p) {
  float4 a = *(const float4*)p;
  float4 b = *(const float4*)(p + 4);
  bf16x8 f;
  f[0] = bfs(a.x); f[1] = bfs(a.y); f[2] = bfs(a.z); f[3] = bfs(a.w);
  f[4] = bfs(b.x); f[5] = bfs(b.y); f[6] = bfs(b.z); f[7] = bfs(b.w);
  return f;
}

// ================= pack kernel (grid 64): coalesced f32 reads -> fragment-order bf16 ====
// frag layout: lane (= g*16 + l15) of fragment (head,nt,kt) holds
//   W[o = head*64 + nt*16 + l15][k = g*8 + kt*32 + j], j=0..7
__global__ __launch_bounds__(256, 2) void
pack_kernel(const float* __restrict__ Wk, const float* __restrict__ Wq,
            const float* __restrict__ Wv, short* __restrict__ dstall)
{
  const int blk = blockIdx.x;
  const int tid = threadIdx.x;
  const int m = blk >> 4, sub = blk & 15;
  const float* src; int stride, off, dsto;
  if (m == 0)      { src = Wk; stride = 64;  off = 0;  dsto = WKP_S; }
  else if (m == 1) { src = Wv; stride = 128; off = 0;  dsto = WVP_S; }   // Wv kv-part
  else if (m == 2) { src = Wq; stride = 64;  off = 0;  dsto = WQP_S; }
  else             { src = Wv; stride = 128; off = 64; dsto = WVQP_S; }  // Wv q-part
  short* dst = dstall + dsto;
  int i4 = sub * 256 + tid;               // float4 index in 256x64 submatrix
  int o = i4 >> 4, c4 = i4 & 15;
  float4 v = ((const float4*)(src + o * stride + off))[c4];
  int k0 = c4 * 4;
  int kt = k0 >> 5, gg = (k0 & 31) >> 3, j0 = k0 & 7;
  int head = o >> 6, nt = (o >> 4) & 3, ol = o & 15;
  int di = ((((head * 4 + nt) * 2 + kt) * 64) + gg * 16 + ol) * 8 + j0;
  *(uint2*)(dst + di) = make_uint2(packbf2(v.x, v.y), packbf2(v.z, v.w));
}

// ================= main kernel (grid 1024, wave = head) =================
// Orientation: mfma(W_frag, kv_frag) -> C[o = g*4+r][n = l15].
// Register budget: target <=128 total (VGPR+acc) for 4 waves/EU, single
// co-resident dispatch pass. Transients bounded: mt loops unroll 1,
// prologue weight loops unroll 2; bk/bw never coexist.
template <int PREP>
__global__ __launch_bounds__(256, 4) void
rnn_attn_kernel(const float* __restrict__ q_x, const float* __restrict__ kv_x,
                const float* __restrict__ Wk, const float* __restrict__ Wq,
                const float* __restrict__ Wv, const float* __restrict__ bv,
                const float* __restrict__ bias, const float* __restrict__ wsc,
                const short* __restrict__ pack, float* __restrict__ out)
{
  __shared__ __align__(16) unsigned char Atile[128 * 128];
  __shared__ float4 qv_lds[4][4][4];   // [head][nt][g]

  const int tid = threadIdx.x;
  const int bt = blockIdx.x;
  const int lane = tid & 63;
  const int head = tid >> 6;
  const int l15 = lane & 15;
  const int g = lane >> 4;

  // ---- stage kv tile (127x64 f32 -> bf16, XOR-swizzled), coalesced ----
  const float* kv = kv_x + (size_t)bt * (NB * 64);
  #pragma unroll
  for (int i = 0; i < 8; ++i) {
    int idx = i * 256 + tid;
    int row = idx >> 4, c = idx & 15;
    float4 v = (row < NB) ? ((const float4*)kv)[idx] : make_float4(0.f, 0.f, 0.f, 0.f);
    int byte = (row << 7) + (c << 3);
    byte ^= ((row & 7) << 4);
    *(uint2*)(&Atile[byte]) = make_uint2(packbf2(v.x, v.y), packbf2(v.z, v.w));
  }

  // ---- prologue: qq/qv via broadcast-B MFMA; bias/bv folded in as C-in ----
  // qq[nt][r] = q@Wq.T[o] + bias[o&63], o = head*64+nt*16+g*4+r (same in all l15)
  f32x4 qq[4];
  {
    bf16x8 qf0 = gath(q_x + bt * 64 + g * 8);
    bf16x8 qf1 = gath(q_x + bt * 64 + 32 + g * 8);
    // qv first: wv-frags die before wq-frags are loaded
    #pragma unroll 2
    for (int nt = 0; nt < 4; ++nt) {
      bf16x8 wv0, wv1;
      if (PREP) {
        const bf16x8* pv = (const bf16x8*)(pack + WVQP_S);
        wv0 = pv[((head * 4 + nt) * 2 + 0) * 64 + lane];
        wv1 = pv[((head * 4 + nt) * 2 + 1) * 64 + lane];
      } else {
        int o = head * 64 + nt * 16 + l15;
        wv0 = gath(Wv + o * 128 + 64 + g * 8);
        wv1 = gath(Wv + o * 128 + 64 + 32 + g * 8);
      }
      float4 bv4 = ((const float4*)(bv + head * 64))[nt * 4 + g];
      f32x4 b = (f32x4){bv4.x, bv4.y, bv4.z, bv4.w};
      b = __builtin_amdgcn_mfma_f32_16x16x32_bf16(wv0, qf0, b, 0, 0, 0);
      b = __builtin_amdgcn_mfma_f32_16x16x32_bf16(wv1, qf1, b, 0, 0, 0);
      if (l15 == 0) qv_lds[head][nt][g] = make_float4(b[0], b[1], b[2], b[3]);
    }
    #pragma unroll 2
    for (int nt = 0; nt < 4; ++nt) {
      bf16x8 wq0, wq1;
      if (PREP) {
        const bf16x8* pw = (const bf16x8*)(pack + WQP_S);
        wq0 = pw[((head * 4 + nt) * 2 + 0) * 64 + lane];
        wq1 = pw[((head * 4 + nt) * 2 + 1) * 64 + lane];
      } else {
        int o = head * 64 + nt * 16 + l15;
        wq0 = gath(Wq + o * 64 + g * 8);
        wq1 = gath(Wq + o * 64 + 32 + g * 8);
      }
      float4 bs4 = ((const float4*)bias)[nt * 4 + g];
      f32x4 a = (f32x4){bs4.x, bs4.y, bs4.z, bs4.w};
      a = __builtin_amdgcn_mfma_f32_16x16x32_bf16(wq0, qf0, a, 0, 0, 0);
      a = __builtin_amdgcn_mfma_f32_16x16x32_bf16(wq1, qf1, a, 0, 0, 0);
      qq[nt] = a;
    }
  }

  // ---- score weights, pre-scaled by -2 (the Sigma(ws) term cancels in softmax):
  //   score'_n = sum_o (-2 ws[o]) / (e^{2x}+1)   ==  score_n - Sigma(ws)
  f32x4 ws4[4];
  bf16x8 bk[4][2];
  #pragma unroll 2
  for (int nt = 0; nt < 4; ++nt) {
    float4 t = ((const float4*)wsc)[nt * 4 + g];
    ws4[nt] = (f32x4){-2.f * t.x, -2.f * t.y, -2.f * t.z, -2.f * t.w};
    if (PREP) {
      const bf16x8* pw = (const bf16x8*)(pack + WKP_S);
      bk[nt][0] = pw[((head * 4 + nt) * 2 + 0) * 64 + lane];
      bk[nt][1] = pw[((head * 4 + nt) * 2 + 1) * 64 + lane];
    } else {
      int o = head * 64 + nt * 16 + l15;
      bk[nt][0] = gath(Wk + o * 64 + g * 8);
      bk[nt][1] = gath(Wk + o * 64 + 32 + g * 8);
    }
  }

  __syncthreads();

  // ---- Phase C: keys^T GEMM + score; score[n=mt*16+l15] in register sr[mt] ----
  float sr[8];
  #pragma unroll 1
  for (int mt = 0; mt < 8; ++mt) {
    int row = mt * 16 + l15;
    int byte0 = (row << 7) + g * 16;
    int swz = (l15 & 7) << 4;
    bf16x8 a0 = *(const bf16x8*)(&Atile[byte0 ^ swz]);
    bf16x8 a1 = *(const bf16x8*)(&Atile[(byte0 + 64) ^ swz]);
    float p = 0.f;
    #pragma unroll
    for (int nt = 0; nt < 4; ++nt) {
      f32x4 acc = qq[nt];    // C-in = queries + bias (broadcast over cols)
      acc = __builtin_amdgcn_mfma_f32_16x16x32_bf16(bk[nt][0], a0, acc, 0, 0, 0);
      acc = __builtin_amdgcn_mfma_f32_16x16x32_bf16(bk[nt][1], a1, acc, 0, 0, 0);
      #pragma unroll
      for (int r = 0; r < 4; ++r) {
        float e = __expf(2.f * acc[r]);
        p = fmaf(ws4[nt][r], __builtin_amdgcn_rcpf(e + 1.f), p);
      }
    }
    p += __shfl_xor(p, 16);    // reduce over o across g-groups
    p += __shfl_xor(p, 32);
    sr[mt] = p;                // full score (shifted by -Sigma ws), same in all g
  }

  // ---- Phase D: softmax over n=127 (regs + 8 shfl total) ----
  if (l15 == 15) sr[7] = -3.0e38f;        // mask pad row n=127
  float m = fmaxf(fmaxf(fmaxf(sr[0], sr[1]), fmaxf(sr[2], sr[3])),
                  fmaxf(fmaxf(sr[4], sr[5]), fmaxf(sr[6], sr[7])));
  #pragma unroll
  for (int d = 1; d < 16; d <<= 1) m = fmaxf(m, __shfl_xor(m, d));
  float sum = 0.f;
  #pragma unroll
  for (int mt = 0; mt < 8; ++mt) { sr[mt] = __expf(sr[mt] - m); sum += sr[mt]; }
  #pragma unroll
  for (int d = 1; d < 16; d <<= 1) sum += __shfl_xor(sum, d);
  float inv = __builtin_amdgcn_rcpf(sum);
  #pragma unroll
  for (int mt = 0; mt < 8; ++mt) sr[mt] *= inv;   // softmax weight for n=mt*16+l15

  // ---- Phase E: V^T GEMM + weighted accumulate (weights lane-local, zero shfl) ----
  // bw loaded only now: bk is dead, so bk/bw never coexist.
  bf16x8 bw[4][2];
  if (PREP) {
    const bf16x8* pw = (const bf16x8*)(pack + WVP_S);
    #pragma unroll 2
    for (int nt = 0; nt < 4; ++nt) {
      bw[nt][0] = pw[((head * 4 + nt) * 2 + 0) * 64 + lane];
      bw[nt][1] = pw[((head * 4 + nt) * 2 + 1) * 64 + lane];
    }
  } else {
    #pragma unroll 2
    for (int nt = 0; nt < 4; ++nt) {
      int o = head * 64 + nt * 16 + l15;
      bw[nt][0] = gath(Wv + o * 128 + g * 8);
      bw[nt][1] = gath(Wv + o * 128 + 32 + g * 8);
    }
  }

  f32x4 cs[4];
  #pragma unroll
  for (int nt = 0; nt < 4; ++nt) cs[nt] = (f32x4){0.f, 0.f, 0.f, 0.f};
  #pragma unroll 1
  for (int mt = 0; mt < 8; ++mt) {
    int row = mt * 16 + l15;
    int byte0 = (row << 7) + g * 16;
    int swz = (l15 & 7) << 4;
    bf16x8 a0 = *(const bf16x8*)(&Atile[byte0 ^ swz]);
    bf16x8 a1 = *(const bf16x8*)(&Atile[(byte0 + 64) ^ swz]);
    float wgt = sr[mt];
    #pragma unroll
    for (int nt = 0; nt < 4; ++nt) {
      f32x4 vac = (f32x4){0.f, 0.f, 0.f, 0.f};
      vac = __builtin_amdgcn_mfma_f32_16x16x32_bf16(bw[nt][0], a0, vac, 0, 0, 0);
      vac = __builtin_amdgcn_mfma_f32_16x16x32_bf16(bw[nt][1], a1, vac, 0, 0, 0);
      #pragma unroll
      for (int r = 0; r < 4; ++r) cs[nt][r] = fmaf(vac[r], wgt, cs[nt][r]);
    }
  }

  // ---- final reduce over l15, add stashed qv, store ----
  #pragma unroll
  for (int nt = 0; nt < 4; ++nt) {
    #pragma unroll
    for (int d = 1; d < 16; d <<= 1) {
      #pragma unroll
      for (int r = 0; r < 4; ++r) cs[nt][r] += __shfl_xor(cs[nt][r], d);
    }
  }
  if (l15 == 0) {
    #pragma unroll
    for (int nt = 0; nt < 4; ++nt) {
      float4 qv4 = qv_lds[head][nt][g];
      float4 o4 = make_float4(cs[nt][0] + qv4.x, cs[nt][1] + qv4.y,
                              cs[nt][2] + qv4.z, cs[nt][3] + qv4.w);
      ((float4*)out)[bt * 64 + head * 16 + nt * 4 + g] = o4;
    }
  }
}

extern "C" void kernel_launch(void* const* d_in, const int* in_sizes, int n_in,
                              void* d_out, int out_size, void* d_ws, size_t ws_size,
                              hipStream_t stream) {
  const float* q_x  = (const float*)d_in[0];
  const float* kv_x = (const float*)d_in[1];
  const float* Wk   = (const float*)d_in[2];
  const float* Wq   = (const float*)d_in[3];
  const float* Wv   = (const float*)d_in[4];
  const float* bv   = (const float*)d_in[5];
  const float* bias = (const float*)d_in[6];
  const float* wsc  = (const float*)d_in[7];
  // d_in[8] = bs: constant across neighbors -> cancels in softmax, unused.
  float* out = (float*)d_out;
  short* pack = (short*)d_ws;

  if (ws_size >= WS_NEEDED) {
    pack_kernel<<<64, 256, 0, stream>>>(Wk, Wq, Wv, pack);
    rnn_attn_kernel<1><<<1024, 256, 0, stream>>>(q_x, kv_x, Wk, Wq, Wv, bv, bias, wsc, pack, out);
  } else {
    rnn_attn_kernel<0><<<1024, 256, 0, stream>>>(q_x, kv_x, Wk, Wq, Wv, bv, bias, wsc, pack, out);
  }
}

// Round 8
// 30.902 us; speedup vs baseline: 4.6347x; 4.6347x over previous
//
#include <hip/hip_runtime.h>
#include <hip/hip_bf16.h>

// Problem constants: B=8, T=128, n=127 neighbors, Q=K=64, H=4, O=H*K=256
#define NB 127
#define SCALE 2.885390081777927f   // 2*log2(e): folds tanh's e^{2x} into one exp2

typedef __attribute__((ext_vector_type(8))) short bf16x8;
typedef __attribute__((ext_vector_type(4))) float f32x4;

// ws layout: packed bf16 MFMA fragments, 4 x 32KB (short offsets).
// Wk and Wq are PRE-SCALED by SCALE in the pack kernel.
#define WKP_S  0
#define WVP_S  16384
#define WQP_S  32768
#define WVQP_S 49152
#define WS_NEEDED ((size_t)(4 * 16384 * 2))

__device__ __forceinline__ short bfs(float f) {
  __hip_bfloat16 h = __float2bfloat16(f);
  return __builtin_bit_cast(short, h);
}
__device__ __forceinline__ unsigned packbf2(float a, float b) {
  unsigned lo = (unsigned short)bfs(a);
  unsigned hi = (unsigned short)bfs(b);
  return lo | (hi << 16);
}
__device__ __forceinline__ bf16x8 gath_s(const float* __restrict__ p, float s) {
  float4 a = *(const float4*)p;
  float4 b = *(const float4*)(p + 4);
  bf16x8 f;
  f[0] = bfs(a.x * s); f[1] = bfs(a.y * s); f[2] = bfs(a.z * s); f[3] = bfs(a.w * s);
  f[4] = bfs(b.x * s); f[5] = bfs(b.y * s); f[6] = bfs(b.z * s); f[7] = bfs(b.w * s);
  return f;
}

// ================= pack kernel (grid 64): coalesced f32 reads -> fragment-order bf16 ====
// frag layout: lane (= g*16 + l15) of fragment (head,nt,kt) holds
//   W[o = head*64 + nt*16 + l15][k = g*8 + kt*32 + j], j=0..7
__global__ __launch_bounds__(256, 2) void
pack_kernel(const float* __restrict__ Wk, const float* __restrict__ Wq,
            const float* __restrict__ Wv, short* __restrict__ dstall)
{
  const int blk = blockIdx.x;
  const int tid = threadIdx.x;
  const int m = blk >> 4, sub = blk & 15;
  const float* src; int stride, off, dsto; float scl;
  if (m == 0)      { src = Wk; stride = 64;  off = 0;  dsto = WKP_S;  scl = SCALE; }
  else if (m == 1) { src = Wv; stride = 128; off = 0;  dsto = WVP_S;  scl = 1.f; }  // Wv kv
  else if (m == 2) { src = Wq; stride = 64;  off = 0;  dsto = WQP_S;  scl = SCALE; }
  else             { src = Wv; stride = 128; off = 64; dsto = WVQP_S; scl = 1.f; }  // Wv q
  short* dst = dstall + dsto;
  int i4 = sub * 256 + tid;               // float4 index in 256x64 submatrix
  int o = i4 >> 4, c4 = i4 & 15;
  float4 v = ((const float4*)(src + o * stride + off))[c4];
  int k0 = c4 * 4;
  int kt = k0 >> 5, gg = (k0 & 31) >> 3, j0 = k0 & 7;
  int head = o >> 6, nt = (o >> 4) & 3, ol = o & 15;
  int di = ((((head * 4 + nt) * 2 + kt) * 64) + gg * 16 + ol) * 8 + j0;
  *(uint2*)(dst + di) = make_uint2(packbf2(v.x * scl, v.y * scl),
                                   packbf2(v.z * scl, v.w * scl));
}

// ================= main kernel (grid 1024, wave = head) =================
// Orientation: mfma(W_frag, kv_frag) -> C[o = g*4+r][n = l15].
// Register budget: two o-half passes (only 2 of 4 weight frags live), scores
// in wave-private LDS (no runtime-indexed register arrays anywhere), so
// peak liveness ~80 -> fits the (256,4) 128-reg cap with no spill.
template <int PREP>
__global__ __launch_bounds__(256, 4) void
rnn_attn_kernel(const float* __restrict__ q_x, const float* __restrict__ kv_x,
                const float* __restrict__ Wk, const float* __restrict__ Wq,
                const float* __restrict__ Wv, const float* __restrict__ bv,
                const float* __restrict__ bias, const float* __restrict__ wsc,
                const short* __restrict__ pack, float* __restrict__ out)
{
  __shared__ __align__(16) unsigned char Atile[128 * 128];
  __shared__ float scs[4][128];        // per-head scores -> then softmax weights
  __shared__ float4 qv_lds[4][4][4];   // [head][nt][g]

  const int tid = threadIdx.x;
  const int bt = blockIdx.x;
  const int lane = tid & 63;
  const int head = tid >> 6;
  const int l15 = lane & 15;
  const int g = lane >> 4;

  // ---- stage kv tile (127x64 f32 -> bf16, XOR-swizzled), coalesced ----
  const float* kv = kv_x + (size_t)bt * (NB * 64);
  #pragma unroll
  for (int i = 0; i < 8; ++i) {
    int idx = i * 256 + tid;
    int row = idx >> 4, c = idx & 15;
    float4 v = (row < NB) ? ((const float4*)kv)[idx] : make_float4(0.f, 0.f, 0.f, 0.f);
    int byte = (row << 7) + (c << 3);
    byte ^= ((row & 7) << 4);
    *(uint2*)(&Atile[byte]) = make_uint2(packbf2(v.x, v.y), packbf2(v.z, v.w));
  }

  // ---- prologue: qq/qv via broadcast-B MFMA ----
  // qq[nt][r] = SCALE*(q@Wq.T[o] + bias[o&63]), o = head*64+nt*16+g*4+r
  f32x4 qq[4];
  {
    bf16x8 qf0 = gath_s(q_x + bt * 64 + g * 8, 1.f);
    bf16x8 qf1 = gath_s(q_x + bt * 64 + 32 + g * 8, 1.f);
    // qv first: wv-frags die before wq-frags are loaded
    #pragma unroll
    for (int nt = 0; nt < 4; ++nt) {
      bf16x8 wv0, wv1;
      if (PREP) {
        const bf16x8* pv = (const bf16x8*)(pack + WVQP_S);
        wv0 = pv[((head * 4 + nt) * 2 + 0) * 64 + lane];
        wv1 = pv[((head * 4 + nt) * 2 + 1) * 64 + lane];
      } else {
        int o = head * 64 + nt * 16 + l15;
        wv0 = gath_s(Wv + o * 128 + 64 + g * 8, 1.f);
        wv1 = gath_s(Wv + o * 128 + 64 + 32 + g * 8, 1.f);
      }
      float4 bv4 = ((const float4*)(bv + head * 64))[nt * 4 + g];
      f32x4 b = (f32x4){bv4.x, bv4.y, bv4.z, bv4.w};
      b = __builtin_amdgcn_mfma_f32_16x16x32_bf16(wv0, qf0, b, 0, 0, 0);
      b = __builtin_amdgcn_mfma_f32_16x16x32_bf16(wv1, qf1, b, 0, 0, 0);
      if (l15 == 0) qv_lds[head][nt][g] = make_float4(b[0], b[1], b[2], b[3]);
    }
    #pragma unroll
    for (int nt = 0; nt < 4; ++nt) {
      bf16x8 wq0, wq1;
      if (PREP) {
        const bf16x8* pw = (const bf16x8*)(pack + WQP_S);
        wq0 = pw[((head * 4 + nt) * 2 + 0) * 64 + lane];
        wq1 = pw[((head * 4 + nt) * 2 + 1) * 64 + lane];
      } else {
        int o = head * 64 + nt * 16 + l15;
        wq0 = gath_s(Wq + o * 64 + g * 8, SCALE);
        wq1 = gath_s(Wq + o * 64 + 32 + g * 8, SCALE);
      }
      float4 bs4 = ((const float4*)bias)[nt * 4 + g];
      f32x4 a = (f32x4){bs4.x * SCALE, bs4.y * SCALE, bs4.z * SCALE, bs4.w * SCALE};
      a = __builtin_amdgcn_mfma_f32_16x16x32_bf16(wq0, qf0, a, 0, 0, 0);
      a = __builtin_amdgcn_mfma_f32_16x16x32_bf16(wq1, qf1, a, 0, 0, 0);
      qq[nt] = a;
    }
  }

  __syncthreads();

  // ---- Phase C: keys^T GEMM + score, two o-halves (16 regs of frags live) ----
  // score'_n = sum_o (-2 ws_o) / (exp2(acc)+1), acc = SCALE*(keys+queries+bias)
  #pragma unroll
  for (int h = 0; h < 2; ++h) {
    bf16x8 b00, b01, b10, b11;
    if (PREP) {
      const bf16x8* pw = (const bf16x8*)(pack + WKP_S);
      b00 = pw[((head * 4 + 2 * h + 0) * 2 + 0) * 64 + lane];
      b01 = pw[((head * 4 + 2 * h + 0) * 2 + 1) * 64 + lane];
      b10 = pw[((head * 4 + 2 * h + 1) * 2 + 0) * 64 + lane];
      b11 = pw[((head * 4 + 2 * h + 1) * 2 + 1) * 64 + lane];
    } else {
      int o0 = head * 64 + (2 * h) * 16 + l15;
      b00 = gath_s(Wk + o0 * 64 + g * 8, SCALE);
      b01 = gath_s(Wk + o0 * 64 + 32 + g * 8, SCALE);
      b10 = gath_s(Wk + (o0 + 16) * 64 + g * 8, SCALE);
      b11 = gath_s(Wk + (o0 + 16) * 64 + 32 + g * 8, SCALE);
    }
    float4 ta = ((const float4*)wsc)[(2 * h) * 4 + g];
    float4 tb = ((const float4*)wsc)[(2 * h + 1) * 4 + g];
    f32x4 wsa = (f32x4){-2.f * ta.x, -2.f * ta.y, -2.f * ta.z, -2.f * ta.w};
    f32x4 wsb = (f32x4){-2.f * tb.x, -2.f * tb.y, -2.f * tb.z, -2.f * tb.w};
    f32x4 qa = qq[2 * h], qb = qq[2 * h + 1];

    #pragma unroll 1
    for (int mt = 0; mt < 8; ++mt) {
      int row = mt * 16 + l15;
      int byte0 = (row << 7) + g * 16;
      int swz = (l15 & 7) << 4;
      bf16x8 a0 = *(const bf16x8*)(&Atile[byte0 ^ swz]);
      bf16x8 a1 = *(const bf16x8*)(&Atile[(byte0 + 64) ^ swz]);
      float p = 0.f;
      f32x4 acc = qa;
      acc = __builtin_amdgcn_mfma_f32_16x16x32_bf16(b00, a0, acc, 0, 0, 0);
      acc = __builtin_amdgcn_mfma_f32_16x16x32_bf16(b01, a1, acc, 0, 0, 0);
      #pragma unroll
      for (int r = 0; r < 4; ++r)
        p = fmaf(wsa[r], __builtin_amdgcn_rcpf(__builtin_amdgcn_exp2f(acc[r]) + 1.f), p);
      f32x4 acc2 = qb;
      acc2 = __builtin_amdgcn_mfma_f32_16x16x32_bf16(b10, a0, acc2, 0, 0, 0);
      acc2 = __builtin_amdgcn_mfma_f32_16x16x32_bf16(b11, a1, acc2, 0, 0, 0);
      #pragma unroll
      for (int r = 0; r < 4; ++r)
        p = fmaf(wsb[r], __builtin_amdgcn_rcpf(__builtin_amdgcn_exp2f(acc2[r]) + 1.f), p);
      p += __shfl_xor(p, 16);    // sum over o across g-groups
      p += __shfl_xor(p, 32);
      if (g == 0) {
        int idx = mt * 16 + l15;
        scs[head][idx] = h ? (scs[head][idx] + p) : p;
      }
    }
  }

  // ---- Phase D: softmax over n=127 (wave-private, static offsets only) ----
  {
    float s0 = scs[head][l15 + 0],  s1 = scs[head][l15 + 16];
    float s2 = scs[head][l15 + 32], s3 = scs[head][l15 + 48];
    float s4 = scs[head][l15 + 64], s5 = scs[head][l15 + 80];
    float s6 = scs[head][l15 + 96], s7 = scs[head][l15 + 112];
    if (l15 == 15) s7 = -3.0e38f;   // mask pad row n=127
    float m = fmaxf(fmaxf(fmaxf(s0, s1), fmaxf(s2, s3)),
                    fmaxf(fmaxf(s4, s5), fmaxf(s6, s7)));
    #pragma unroll
    for (int d = 1; d < 16; d <<= 1) m = fmaxf(m, __shfl_xor(m, d));
    float e0 = __expf(s0 - m), e1 = __expf(s1 - m), e2 = __expf(s2 - m), e3 = __expf(s3 - m);
    float e4 = __expf(s4 - m), e5 = __expf(s5 - m), e6 = __expf(s6 - m), e7 = __expf(s7 - m);
    float sum = ((e0 + e1) + (e2 + e3)) + ((e4 + e5) + (e6 + e7));
    #pragma unroll
    for (int d = 1; d < 16; d <<= 1) sum += __shfl_xor(sum, d);
    float inv = __builtin_amdgcn_rcpf(sum);
    if (g == 0) {
      scs[head][l15 + 0]  = e0 * inv; scs[head][l15 + 16] = e1 * inv;
      scs[head][l15 + 32] = e2 * inv; scs[head][l15 + 48] = e3 * inv;
      scs[head][l15 + 64] = e4 * inv; scs[head][l15 + 80] = e5 * inv;
      scs[head][l15 + 96] = e6 * inv; scs[head][l15 + 112] = e7 * inv;
    }
  }

  // ---- Phase E: V^T GEMM + weighted accumulate, two o-halves ----
  #pragma unroll
  for (int h = 0; h < 2; ++h) {
    bf16x8 w00, w01, w10, w11;
    if (PREP) {
      const bf16x8* pw = (const bf16x8*)(pack + WVP_S);
      w00 = pw[((head * 4 + 2 * h + 0) * 2 + 0) * 64 + lane];
      w01 = pw[((head * 4 + 2 * h + 0) * 2 + 1) * 64 + lane];
      w10 = pw[((head * 4 + 2 * h + 1) * 2 + 0) * 64 + lane];
      w11 = pw[((head * 4 + 2 * h + 1) * 2 + 1) * 64 + lane];
    } else {
      int o0 = head * 64 + (2 * h) * 16 + l15;
      w00 = gath_s(Wv + o0 * 128 + g * 8, 1.f);
      w01 = gath_s(Wv + o0 * 128 + 32 + g * 8, 1.f);
      w10 = gath_s(Wv + (o0 + 16) * 128 + g * 8, 1.f);
      w11 = gath_s(Wv + (o0 + 16) * 128 + 32 + g * 8, 1.f);
    }
    f32x4 c0 = (f32x4){0.f, 0.f, 0.f, 0.f};
    f32x4 c1 = (f32x4){0.f, 0.f, 0.f, 0.f};
    #pragma unroll 1
    for (int mt = 0; mt < 8; ++mt) {
      int row = mt * 16 + l15;
      int byte0 = (row << 7) + g * 16;
      int swz = (l15 & 7) << 4;
      bf16x8 a0 = *(const bf16x8*)(&Atile[byte0 ^ swz]);
      bf16x8 a1 = *(const bf16x8*)(&Atile[(byte0 + 64) ^ swz]);
      float w = scs[head][mt * 16 + l15];   // broadcast across g, conflict-free
      f32x4 v = (f32x4){0.f, 0.f, 0.f, 0.f};
      v = __builtin_amdgcn_mfma_f32_16x16x32_bf16(w00, a0, v, 0, 0, 0);
      v = __builtin_amdgcn_mfma_f32_16x16x32_bf16(w01, a1, v, 0, 0, 0);
      #pragma unroll
      for (int r = 0; r < 4; ++r) c0[r] = fmaf(v[r], w, c0[r]);
      f32x4 v2 = (f32x4){0.f, 0.f, 0.f, 0.f};
      v2 = __builtin_amdgcn_mfma_f32_16x16x32_bf16(w10, a0, v2, 0, 0, 0);
      v2 = __builtin_amdgcn_mfma_f32_16x16x32_bf16(w11, a1, v2, 0, 0, 0);
      #pragma unroll
      for (int r = 0; r < 4; ++r) c1[r] = fmaf(v2[r], w, c1[r]);
    }
    // reduce over n (= l15) and store this half's 32 o-values
    #pragma unroll
    for (int d = 1; d < 16; d <<= 1) {
      #pragma unroll
      for (int r = 0; r < 4; ++r) {
        c0[r] += __shfl_xor(c0[r], d);
        c1[r] += __shfl_xor(c1[r], d);
      }
    }
    if (l15 == 0) {
      float4 qv4 = qv_lds[head][2 * h][g];
      float4 o4 = make_float4(c0[0] + qv4.x, c0[1] + qv4.y, c0[2] + qv4.z, c0[3] + qv4.w);
      ((float4*)out)[bt * 64 + head * 16 + (2 * h) * 4 + g] = o4;
      float4 qv5 = qv_lds[head][2 * h + 1][g];
      float4 o5 = make_float4(c1[0] + qv5.x, c1[1] + qv5.y, c1[2] + qv5.z, c1[3] + qv5.w);
      ((float4*)out)[bt * 64 + head * 16 + (2 * h + 1) * 4 + g] = o5;
    }
  }
}

extern "C" void kernel_launch(void* const* d_in, const int* in_sizes, int n_in,
                              void* d_out, int out_size, void* d_ws, size_t ws_size,
                              hipStream_t stream) {
  const float* q_x  = (const float*)d_in[0];
  const float* kv_x = (const float*)d_in[1];
  const float* Wk   = (const float*)d_in[2];
  const float* Wq   = (const float*)d_in[3];
  const float* Wv   = (const float*)d_in[4];
  const float* bv   = (const float*)d_in[5];
  const float* bias = (const float*)d_in[6];
  const float* wsc  = (const float*)d_in[7];
  // d_in[8] = bs: constant across neighbors -> cancels in softmax, unused.
  float* out = (float*)d_out;
  short* pack = (short*)d_ws;

  if (ws_size >= WS_NEEDED) {
    pack_kernel<<<64, 256, 0, stream>>>(Wk, Wq, Wv, pack);
    rnn_attn_kernel<1><<<1024, 256, 0, stream>>>(q_x, kv_x, Wk, Wq, Wv, bv, bias, wsc, pack, out);
  } else {
    rnn_attn_kernel<0><<<1024, 256, 0, stream>>>(q_x, kv_x, Wk, Wq, Wv, bv, bias, wsc, pack, out);
  }
}